// Round 3
// baseline (593.458 us; speedup 1.0000x reference)
//
#include <hip/hip_runtime.h>
#include <cstdint>

// Per-pixel channel permutation, image (C=16, W=2048, H=2048) f32.
// out[k,i,j] = image[perm[i,j,k], i, j], perm = stable argsort over channels of
// jax.random.uniform(key(1), (W,H,C)) with threefry_partitionable=True:
//   bits[i] = x0 ^ x1 of threefry2x32(key=(0,1), ctr=(hi32(i), lo32(i))), i = flat index
//   float order == order of (bits >> 9)

#define NPIX 4194304u  // 2048*2048

// threefry2x32, key=(0,1), counter=(0, c1); returns x0 ^ x1.
__device__ __forceinline__ uint32_t tf_bits(uint32_t c1) {
  const uint32_t KS2 = 0x1BD11BDBu;  // 0 ^ 1 ^ 0x1BD11BDA
  uint32_t x0 = 0u;        // c0(=0) + ks0(=0)
  uint32_t x1 = c1 + 1u;   // c1 + ks1(=1)
#define TF_ROT(x, r) (((x) << (r)) | ((x) >> (32 - (r))))
#define TF_RND(r) { x0 += x1; x1 = TF_ROT(x1, r); x1 ^= x0; }
  TF_RND(13) TF_RND(15) TF_RND(26) TF_RND(6)
  x0 += 1u;   x1 += KS2 + 1u;          // ks[1], ks[2]+1
  TF_RND(17) TF_RND(29) TF_RND(16) TF_RND(24)
  x0 += KS2;  x1 += 2u;                // ks[2], ks[0]+2
  TF_RND(13) TF_RND(15) TF_RND(26) TF_RND(6)
  /* +ks[0]=0 */ x1 += 4u;             // ks[0], ks[1]+3
  TF_RND(17) TF_RND(29) TF_RND(16) TF_RND(24)
  x0 += 1u;   x1 += KS2 + 4u;          // ks[1], ks[2]+4
  TF_RND(13) TF_RND(15) TF_RND(26) TF_RND(6)
  x0 += KS2;  x1 += 5u;                // ks[2], ks[0]+5
#undef TF_RND
#undef TF_ROT
  return x0 ^ x1;
}

__global__ __launch_bounds__(256) void
ppcp_kernel(const float* __restrict__ img, float* __restrict__ out) {
  const uint32_t p = blockIdx.x * 256u + threadIdx.x;  // pixel index [0, NPIX)
  const uint32_t cbase = p * 16u;

  // Issue coalesced loads first; RNG compute hides their latency.
  float v[16];
#pragma unroll
  for (int k = 0; k < 16; ++k) v[k] = img[(size_t)k * NPIX + p];

  // 23-bit comparison keys (float order == (bits>>9) order, ties included).
  uint32_t m[16];
#pragma unroll
  for (int k = 0; k < 16; ++k) m[k] = tf_bits(cbase + (uint32_t)k) >> 9;

  // Stable rank: rank[k] = #{j: m[j] < m[k]} + #{j < k: m[j] == m[k]}.
  int rank[16];
#pragma unroll
  for (int k = 0; k < 16; ++k) rank[k] = k;
#pragma unroll
  for (int a = 0; a < 15; ++a) {
#pragma unroll
    for (int b = a + 1; b < 16; ++b) {
      int c = (m[b] < m[a]) ? 1 : 0;
      rank[a] += c;
      rank[b] -= c;
    }
  }

  // Scatter: out[rank[k]] = v[k]  <=>  out[r] = v[argsort(m)[r]] (stable).
#pragma unroll
  for (int k = 0; k < 16; ++k)
    out[(size_t)rank[k] * NPIX + p] = v[k];
}

extern "C" void kernel_launch(void* const* d_in, const int* in_sizes, int n_in,
                              void* d_out, int out_size, void* d_ws, size_t ws_size,
                              hipStream_t stream) {
  const float* img = (const float*)d_in[0];
  float* out = (float*)d_out;
  ppcp_kernel<<<dim3(NPIX / 256u), dim3(256), 0, stream>>>(img, out);
}

// Round 4
// 483.733 us; speedup vs baseline: 1.2268x; 1.2268x over previous
//
#include <hip/hip_runtime.h>
#include <cstdint>

// Per-pixel channel permutation, image (C=16, W=2048, H=2048) f32.
// out[k,i,j] = image[perm[i,j,k], i, j], perm = stable argsort over channels of
// jax.random.uniform(key(1), (W,H,C)) with threefry_partitionable=True:
//   bits[i] = x0 ^ x1 of threefry2x32(key=(0,1), ctr=(0, i)), i = 16*pixel + k
//   float order == order of (bits >> 9)
//
// R3: scatter stores (~44 txns/inst) were the stall (VALUBusy 54%, BW 17%).
// Route values through a private LDS stripe: scatter in LDS, re-read
// sequentially, store coalesced. Stripe padded to 17 floats -> sequential
// re-read is exactly 2 lanes/bank (free); scatter write ~4-way (cheap).

#define NPIX 4194304u  // 2048*2048

// threefry2x32, key=(0,1), counter=(0, c1); returns x0 ^ x1.
__device__ __forceinline__ uint32_t tf_bits(uint32_t c1) {
  const uint32_t KS2 = 0x1BD11BDBu;  // 0 ^ 1 ^ 0x1BD11BDA
  uint32_t x0 = 0u;        // c0(=0) + ks0(=0)
  uint32_t x1 = c1 + 1u;   // c1 + ks1(=1)
#define TF_ROT(x, r) (((x) << (r)) | ((x) >> (32 - (r))))
#define TF_RND(r) { x0 += x1; x1 = TF_ROT(x1, r); x1 ^= x0; }
  TF_RND(13) TF_RND(15) TF_RND(26) TF_RND(6)
  x0 += 1u;   x1 += KS2 + 1u;          // ks[1], ks[2]+1
  TF_RND(17) TF_RND(29) TF_RND(16) TF_RND(24)
  x0 += KS2;  x1 += 2u;                // ks[2], ks[0]+2
  TF_RND(13) TF_RND(15) TF_RND(26) TF_RND(6)
  /* +ks[0]=0 */ x1 += 4u;             // ks[0], ks[1]+3
  TF_RND(17) TF_RND(29) TF_RND(16) TF_RND(24)
  x0 += 1u;   x1 += KS2 + 4u;          // ks[1], ks[2]+4
  TF_RND(13) TF_RND(15) TF_RND(26) TF_RND(6)
  x0 += KS2;  x1 += 5u;                // ks[2], ks[0]+5
#undef TF_RND
#undef TF_ROT
  return x0 ^ x1;
}

__global__ __launch_bounds__(256) void
ppcp_kernel(const float* __restrict__ img, float* __restrict__ out) {
  __shared__ float buf[256][17];  // 17.4 KB; stripe pad=17 (odd) for bank spread
  const uint32_t tid = threadIdx.x;
  const uint32_t p = blockIdx.x * 256u + tid;  // pixel index [0, NPIX)
  const uint32_t cbase = p * 16u;

  // Coalesced loads issued first; RNG compute hides their latency.
  float v[16];
#pragma unroll
  for (int k = 0; k < 16; ++k) v[k] = img[(size_t)k * NPIX + p];

  // 23-bit comparison keys (float order == (bits>>9) order, ties included).
  uint32_t m[16];
#pragma unroll
  for (int k = 0; k < 16; ++k) m[k] = tf_bits(cbase + (uint32_t)k) >> 9;

  // Stable rank: rank[k] = #{j: m[j] < m[k]} + #{j < k: m[j] == m[k]}.
  int rank[16];
#pragma unroll
  for (int k = 0; k < 16; ++k) rank[k] = k;
#pragma unroll
  for (int a = 0; a < 15; ++a) {
#pragma unroll
    for (int b = a + 1; b < 16; ++b) {
      int c = (m[b] < m[a]) ? 1 : 0;
      rank[a] += c;
      rank[b] -= c;
    }
  }

  // Permute within the private LDS stripe (no cross-thread traffic, no barrier).
  float* stripe = buf[tid];
#pragma unroll
  for (int k = 0; k < 16; ++k) stripe[rank[k]] = v[k];

  // Sequential re-read (2 lanes/bank, conflict-free) -> coalesced stores.
#pragma unroll
  for (int r = 0; r < 16; ++r)
    out[(size_t)r * NPIX + p] = stripe[r];
}

extern "C" void kernel_launch(void* const* d_in, const int* in_sizes, int n_in,
                              void* d_out, int out_size, void* d_ws, size_t ws_size,
                              hipStream_t stream) {
  const float* img = (const float*)d_in[0];
  float* out = (float*)d_out;
  ppcp_kernel<<<dim3(NPIX / 256u), dim3(256), 0, stream>>>(img, out);
}

// Round 5
// 450.722 us; speedup vs baseline: 1.3167x; 1.0732x over previous
//
#include <hip/hip_runtime.h>
#include <cstdint>

// Per-pixel channel permutation, image (C=16, W=2048, H=2048) f32.
// out[k,i,j] = image[perm[i,j,k], i, j], perm = stable argsort over channels of
// jax.random.uniform(key(1), (W,H,C)) with threefry_partitionable=True:
//   bits[i] = x0 ^ x1 of threefry2x32(key=(0,1), ctr=(0, i)), i = 16*pixel + k
//   float order == order of (bits >> 9)
//
// R4 -> R5: VALU-issue-bound (VALUBusy 91%). Cuts:
//  - rotl via v_alignbit_b32 builtin (1 op guaranteed, was possibly 3)
//  - Batcher 63-CE min/max sort of packed keys ((bits>>9)<<4 | k) replaces the
//    120-pair rank network (126 ops vs 360) AND yields the inverse perm, so
//    stores stay coalesced
//  - values staged img -> LDS via global_load_lds (no VGPR roundtrip, no
//    ds_write); buf[16][256] layout makes the indexed re-read bank-conflict-
//    free (bank = tid&31 independent of channel index)

#define NPIX 4194304u  // 2048*2048

__device__ __forceinline__ uint32_t rotl(uint32_t x, int r) {
  // v_alignbit_b32(a,b,c) = ((u64(a)<<32)|b) >> (c&31); a=b=x, c=32-r => rotl(x,r)
  return __builtin_amdgcn_alignbit(x, x, 32 - r);
}

// threefry2x32, key=(0,1), counter=(0, c1); returns x0 ^ x1.
__device__ __forceinline__ uint32_t tf_bits(uint32_t c1) {
  const uint32_t KS2 = 0x1BD11BDBu;  // 0 ^ 1 ^ 0x1BD11BDA
  uint32_t x0 = 0u;        // c0(=0) + ks0(=0)
  uint32_t x1 = c1 + 1u;   // c1 + ks1(=1)
#define TF_RND(r) { x0 += x1; x1 = rotl(x1, r); x1 ^= x0; }
  TF_RND(13) TF_RND(15) TF_RND(26) TF_RND(6)
  x0 += 1u;   x1 += KS2 + 1u;          // ks[1], ks[2]+1
  TF_RND(17) TF_RND(29) TF_RND(16) TF_RND(24)
  x0 += KS2;  x1 += 2u;                // ks[2], ks[0]+2
  TF_RND(13) TF_RND(15) TF_RND(26) TF_RND(6)
  /* +ks[0]=0 */ x1 += 4u;             // ks[0], ks[1]+3
  TF_RND(17) TF_RND(29) TF_RND(16) TF_RND(24)
  x0 += 1u;   x1 += KS2 + 4u;          // ks[1], ks[2]+4
  TF_RND(13) TF_RND(15) TF_RND(26) TF_RND(6)
  x0 += KS2;  x1 += 5u;                // ks[2], ks[0]+5
#undef TF_RND
  return x0 ^ x1;
}

__global__ __launch_bounds__(256) void
ppcp_kernel(const float* __restrict__ img, float* __restrict__ out) {
  __shared__ float buf[16][256];  // 16 KB; column tid is private to its wave
  const uint32_t tid = threadIdx.x;
  const uint32_t wbase = tid & 192u;               // wave id * 64
  const uint32_t p = blockIdx.x * 256u + tid;      // pixel index [0, NPIX)

  // Stage all 16 channel values straight into LDS (async, no VGPR roundtrip).
  // Dest is wave-uniform base + lane*4 -> buf[k][tid]; src is coalesced.
#pragma unroll
  for (int k = 0; k < 16; ++k) {
    __builtin_amdgcn_global_load_lds(
        (const __attribute__((address_space(1))) uint32_t*)(img + (size_t)k * NPIX + p),
        (__attribute__((address_space(3))) uint32_t*)&buf[k][wbase],
        4, 0, 0);
  }

  // Packed sort keys: (23-bit float-order key << 4) | source channel.
  // Distinct by construction => min/max network is stable-argsort-exact.
  const uint32_t cbase = p * 16u;
  uint32_t key[16];
#pragma unroll
  for (int k = 0; k < 16; ++k)
    key[k] = ((tf_bits(cbase + (uint32_t)k) >> 9) << 4) | (uint32_t)k;

  // Batcher odd-even mergesort, n=16: 63 compare-exchanges, min/max only.
#pragma unroll
  for (int pp = 1; pp < 16; pp <<= 1) {
#pragma unroll
    for (int kk = pp; kk >= 1; kk >>= 1) {
#pragma unroll
      for (int j = kk % pp; j + kk < 16; j += 2 * kk) {
#pragma unroll
        for (int i = 0; i < kk; ++i) {
          if (i + j + kk < 16 && (i + j) / (2 * pp) == (i + j + kk) / (2 * pp)) {
            const int a = i + j, b = i + j + kk;
            const uint32_t lo = min(key[a], key[b]);
            const uint32_t hi = max(key[a], key[b]);
            key[a] = lo; key[b] = hi;
          }
        }
      }
    }
  }

  // Wait for the staged values, then gather + coalesced stores.
  // buf[src][tid]: bank = (src*256 + tid) & 31 = tid & 31 -> 2 lanes/bank, free.
  asm volatile("s_waitcnt vmcnt(0)" ::: "memory");
  float* op = out + p;
#pragma unroll
  for (int r = 0; r < 16; ++r) {
    const uint32_t src = key[r] & 15u;   // argsort[r] = source channel for rank r
    op[(size_t)r * NPIX] = buf[src][tid];
  }
}

extern "C" void kernel_launch(void* const* d_in, const int* in_sizes, int n_in,
                              void* d_out, int out_size, void* d_ws, size_t ws_size,
                              hipStream_t stream) {
  const float* img = (const float*)d_in[0];
  float* out = (float*)d_out;
  ppcp_kernel<<<dim3(NPIX / 256u), dim3(256), 0, stream>>>(img, out);
}